// Round 10
// baseline (5798.887 us; speedup 1.0000x reference)
//
#include <hip/hip_runtime.h>

// VanillaVectorQuantizer: N=131072 positions (B=32,H=64,W=64), D=64, K=512.
// enc layout [B, D, H, W]: element (b,d,p) at b*D*HW + d*HW + p, p=h*64+w.
//
// Numerics: EXACT emulation of the numpy fp32 reference chain (verified
// bitwise rounds 2-9, absmax == 0):
//   - M_k: ascending-d fp32 FMA chain (== BLAS sgemm microkernel)
//   - sq_x: numpy pairwise_sum(n=64): 8 stride-8 accumulators of pre-rounded
//     squares (mul then add, NO fma), combine ((r0+r1)+(r2+r3))+((r4+r5)+(r6+r7))
//   - sq_e: sequential d-sum of pre-rounded squares (NO fma)
//   - dist: fl(fl(sq_x - fl(2*M)) + sq_e), contraction off
//   - strict '<' ascending k == np.argmin first-index tie-break
// DO NOT alter these chains.
//
// Per-CU budget model (calibrated on r2/r8's 200us SMEM wall ~2.2 B/cyc and
// the 131k-cyc VALU wall):
//   cb scalar traffic = 1MB/PPT  -> PPT >= 4
//   x  re-read traffic = 67MB/KTILE vs L2 ~56B/cyc -> KTILE >= 8
//   => acc = PPT*KTILE = 32. r9 spilled this footprint (WRITE_SIZE 6.3GB
//   smoking gun) under per-load size_t addressing + (256,4); this version:
//   one base pointer + compile-time offsets, float4-over-4-consecutive-
//   positions x loads (1 load : 32 FMAs), launch_bounds(512,4) (cap 128).
// cb transport: scalar s_load (uniform kt from readfirstlane k-group) —
// the only non-falsified transport. In-block KSPLIT=8 (1 wave/group, 64 ks);
// LDS (best,k) combine ascending group = np.argmin order (r8-proven).

#pragma clang fp contract(off)

#define VQ_D 64
#define VQ_K 512
#define VQ_HW 4096
#define VQ_N 131072
#define NG 8      // k-groups per block (1 wave each)
#define KRANGE 64 // VQ_K / NG
#define KTILE 8
#define PPT 4     // consecutive positions per thread
#define POSB 256  // positions per block = 64 lanes * PPT

__global__ void vq_sqe_kernel(const float* __restrict__ cb,
                              float* __restrict__ sqe) {
    const int k = threadIdx.x;  // 512 threads, one block
    float s = cb[k] * cb[k];    // d = 0 (square rounded, then added: no fma)
    for (int d = 1; d < VQ_D; ++d) {
        const float v = cb[d * VQ_K + k];
        const float sq = v * v;  // contract(off): rounds the square
        s = s + sq;              // then rounds the add (numpy axis-0 reduce)
    }
    sqe[k] = s;
}

__global__ __launch_bounds__(512, 4) void vq_main_kernel(
    const float* __restrict__ enc, const float* __restrict__ cb,
    const float* __restrict__ sqe, float* __restrict__ out) {
    __shared__ float sbest[NG * POSB];  // 8 KB
    __shared__ int sbk[NG * POSB];      // 8 KB

    const int tid = threadIdx.x;
    const int grp = tid >> 6;    // 0..7, == wave id -> wave-uniform
    const int lane = tid & 63;
    const int pos0 = blockIdx.x * POSB;  // 256 | 4096: block within one b
    const int b = pos0 >> 12;
    const int r0 = pos0 & (VQ_HW - 1);
    // This thread's 4 consecutive positions: pos0 + 4*lane + {0,1,2,3}.
    const float* xb = enc + (size_t)b * (VQ_D * VQ_HW) + r0 + 4 * lane;
    float* ob = out + (size_t)b * (VQ_D * VQ_HW) + r0 + 4 * lane;

    // k-range for this wave; readfirstlane -> SGPR, provably uniform ->
    // cb/sqe stay on the scalar-load path.
    const int kbase = __builtin_amdgcn_readfirstlane(grp * KRANGE);

    // sq_x for 4 positions (float4 = component-wise, per-position chains
    // identical to the numpy pairwise_sum emulation).
    float4 pr[8];
#pragma unroll
    for (int j = 0; j < 8; ++j) {
        const float4 v = *reinterpret_cast<const float4*>(xb + j * VQ_HW);
        pr[j] = v * v;  // rounded squares
    }
#pragma unroll
    for (int i8 = 8; i8 < VQ_D; i8 += 8) {
#pragma unroll
        for (int j = 0; j < 8; ++j) {
            const float4 v =
                *reinterpret_cast<const float4*>(xb + (i8 + j) * VQ_HW);
            const float4 sq = v * v;  // rounded squares
            pr[j] += sq;              // rounded adds
        }
    }
    const float4 sqx = ((pr[0] + pr[1]) + (pr[2] + pr[3])) +
                       ((pr[4] + pr[5]) + (pr[6] + pr[7]));

    float best[PPT];
    int bk[PPT];
#pragma unroll
    for (int pp = 0; pp < PPT; ++pp) {
        best[pp] = 3.402823466e38f;
        bk[pp] = 0;
    }

    for (int kt = kbase; kt < kbase + KRANGE; kt += KTILE) {
        float acc[KTILE][PPT];
#pragma unroll
        for (int j = 0; j < KTILE; ++j)
#pragma unroll
            for (int pp = 0; pp < PPT; ++pp) acc[j][pp] = 0.f;

#pragma unroll
        for (int d0 = 0; d0 < VQ_D; d0 += 4) {
            float4 xv[4];  // one float4 load covers all 4 positions at d
#pragma unroll
            for (int dd = 0; dd < 4; ++dd)
                xv[dd] = *reinterpret_cast<const float4*>(xb + (d0 + dd) * VQ_HW);
#pragma unroll
            for (int dd = 0; dd < 4; ++dd) {
#pragma unroll
                for (int j = 0; j < KTILE; ++j) {
                    const float c = cb[(d0 + dd) * VQ_K + kt + j];  // scalar
                    // ascending-d FMA chains (== sgemm), one per position
                    acc[j][0] = fmaf(xv[dd].x, c, acc[j][0]);
                    acc[j][1] = fmaf(xv[dd].y, c, acc[j][1]);
                    acc[j][2] = fmaf(xv[dd].z, c, acc[j][2]);
                    acc[j][3] = fmaf(xv[dd].w, c, acc[j][3]);
                }
            }
        }
#pragma unroll
        for (int j = 0; j < KTILE; ++j) {
            const float se = sqe[kt + j];  // scalar load
            const float dA = (sqx.x - 2.0f * acc[j][0]) + se;  // exact chain
            if (dA < best[0]) { best[0] = dA; bk[0] = kt + j; }
            const float dB = (sqx.y - 2.0f * acc[j][1]) + se;
            if (dB < best[1]) { best[1] = dB; bk[1] = kt + j; }
            const float dC = (sqx.z - 2.0f * acc[j][2]) + se;
            if (dC < best[2]) { best[2] = dC; bk[2] = kt + j; }
            const float dD = (sqx.w - 2.0f * acc[j][3]) + se;
            if (dD < best[3]) { best[3] = dD; bk[3] = kt + j; }
        }
    }

    // Publish per-group results; combine ascending group (= ascending k
    // ranges) with strict '<' == np.argmin first-index semantics.
#pragma unroll
    for (int pp = 0; pp < PPT; ++pp) {
        sbest[grp * POSB + 4 * lane + pp] = best[pp];
        sbk[grp * POSB + 4 * lane + pp] = bk[pp];
    }
    __syncthreads();
    if (tid < POSB) {
        const int p = tid;
        float bb = sbest[p];
        int k0 = sbk[p];
#pragma unroll
        for (int s = 1; s < NG; ++s) {
            const float o = sbest[s * POSB + p];
            if (o < bb) {
                bb = o;
                k0 = sbk[s * POSB + p];
            }
        }
        sbk[p] = k0;  // publish final winner
    }
    __syncthreads();

    int kf[PPT];
#pragma unroll
    for (int pp = 0; pp < PPT; ++pp) kf[pp] = sbk[4 * lane + pp];

    // Each group stores 8 of the 64 d-planes; float4 over 4 consecutive
    // positions -> 16B/lane fully-coalesced stores. cb gathers are L1-hot.
    const int dbase = grp * 8;
#pragma unroll
    for (int dd = 0; dd < 8; ++dd) {
        const int d = dbase + dd;
        float4 o;
        o.x = cb[d * VQ_K + kf[0]];
        o.y = cb[d * VQ_K + kf[1]];
        o.z = cb[d * VQ_K + kf[2]];
        o.w = cb[d * VQ_K + kf[3]];
        *reinterpret_cast<float4*>(ob + (size_t)d * VQ_HW) = o;
    }
}

extern "C" void kernel_launch(void* const* d_in, const int* in_sizes, int n_in,
                              void* d_out, int out_size, void* d_ws, size_t ws_size,
                              hipStream_t stream) {
    const float* enc = (const float*)d_in[0];  // [32,64,64,64]
    const float* cb  = (const float*)d_in[1];  // [64,512]
    float* out = (float*)d_out;
    float* sqe = (float*)d_ws;  // 512 floats

    vq_sqe_kernel<<<1, VQ_K, 0, stream>>>(cb, sqe);
    vq_main_kernel<<<VQ_N / POSB, 512, 0, stream>>>(enc, cb, sqe, out);
}

// Round 11
// 265.161 us; speedup vs baseline: 21.8693x; 21.8693x over previous
//
#include <hip/hip_runtime.h>

// VanillaVectorQuantizer: N=131072 positions (B=32,H=64,W=64), D=64, K=512.
// enc layout [B, D, H, W]: element (b,d,p) at b*D*HW + d*HW + p, p=h*64+w.
//
// Numerics: EXACT emulation of the numpy fp32 reference chain (verified
// bitwise rounds 2-10, absmax == 0):
//   - M_k: ascending-d fp32 FMA chain (== BLAS sgemm microkernel)
//   - sq_x: numpy pairwise_sum(n=64): 8 stride-8 accumulators of pre-rounded
//     squares (mul then add, NO fma), combine ((r0+r1)+(r2+r3))+((r4+r5)+(r6+r7))
//   - sq_e: sequential d-sum of pre-rounded squares (NO fma)
//   - dist: fl(fl(sq_x - fl(2*M)) + sq_e), contraction off
//   - strict '<' ascending k == np.argmin first-index tie-break
// DO NOT alter these chains.
//
// Measured wall: total scalar-pipe cb traffic = waves x cb_bytes_per_wave
// (r2: 2048x128KB = r8: 8192x32KB = 268MB -> 200us @ ~2.2 B/cyc/CU,
// occupancy-invariant). Only PPT cuts it. r9/r10 died of register spill
// (WRITE 6.3GB / FETCH 18.7GB scratch signatures) from occupancy clauses
// ((512,4) -> 64-VGPR cap) + full d-unroll. This round: PPT=4, KSPLIT=2
// -> 1024 waves x 64KB = 67MB SMEM (~120k cyc, at the 131k VALU wall).
// Spill-proofing: NO min-waves clause (r6: compiler allocates 88 fine),
// acc[8][4]=32 static regs, d-loop unroll 2 (<=8 float4 live), x reloaded
// from L1 per K-tile BY DESIGN (r2-proven absorbable).
// Block = 256 thr = {pos-group 0,1} x {k-half 0,1}; 512 pos/block;
// grid = 256 blocks = 1 block/CU. LDS combine, half-0 wins ties = np.argmin.

#pragma clang fp contract(off)

#define VQ_D 64
#define VQ_K 512
#define VQ_HW 4096
#define VQ_N 131072
#define KTILE 8
#define PPT 4
#define POSB 512  // positions per block = 2 groups x 64 lanes x PPT

__global__ void vq_sqe_kernel(const float* __restrict__ cb,
                              float* __restrict__ sqe) {
    const int k = threadIdx.x;  // 512 threads, one block
    float s = cb[k] * cb[k];    // d = 0 (square rounded, then added: no fma)
    for (int d = 1; d < VQ_D; ++d) {
        const float v = cb[d * VQ_K + k];
        const float sq = v * v;  // contract(off): rounds the square
        s = s + sq;              // then rounds the add (numpy axis-0 reduce)
    }
    sqe[k] = s;
}

__global__ __launch_bounds__(256) void vq_main_kernel(
    const float* __restrict__ enc, const float* __restrict__ cb,
    const float* __restrict__ sqe, float* __restrict__ out) {
    __shared__ float sbest[2][POSB];  // [k-half][pos-in-block]  4 KB
    __shared__ int sbk[2][POSB];      //                         4 KB

    const int tid = threadIdx.x;
    const int wid = tid >> 6;     // 0..3
    const int lane = tid & 63;
    const int g = wid >> 1;       // pos-group 0/1 (256 pos each)
    const int h = wid & 1;        // k-half: 0 -> [0,256), 1 -> [256,512)
    const int pos0 = blockIdx.x * POSB;  // 512 | 4096: block within one b
    const int b = pos0 >> 12;
    const int r0 = pos0 & (VQ_HW - 1);
    const int pblk = (g << 8) + 4 * lane;  // first of this thread's 4 pos
    const float* xb = enc + (size_t)b * (VQ_D * VQ_HW) + r0 + pblk;
    float* ob = out + (size_t)b * (VQ_D * VQ_HW) + r0 + pblk;

    // k-range for this wave; readfirstlane -> SGPR, provably uniform ->
    // cb/sqe stay on the scalar-load path (the only viable transport).
    const int kbase = __builtin_amdgcn_readfirstlane(h << 8);

    // sq_x for 4 consecutive positions (float4 = component-wise; chains
    // identical to the numpy pairwise_sum emulation; r10-verified bitwise).
    float4 pr[8];
#pragma unroll
    for (int j = 0; j < 8; ++j) {
        const float4 v = *reinterpret_cast<const float4*>(xb + j * VQ_HW);
        pr[j] = v * v;  // rounded squares
    }
#pragma unroll
    for (int i8 = 8; i8 < VQ_D; i8 += 8) {
#pragma unroll
        for (int j = 0; j < 8; ++j) {
            const float4 v =
                *reinterpret_cast<const float4*>(xb + (i8 + j) * VQ_HW);
            const float4 sq = v * v;  // rounded squares
            pr[j] += sq;              // rounded adds
        }
    }
    const float4 sqx = ((pr[0] + pr[1]) + (pr[2] + pr[3])) +
                       ((pr[4] + pr[5]) + (pr[6] + pr[7]));

    float best0 = 3.402823466e38f, best1 = best0, best2 = best0, best3 = best0;
    int bk0 = 0, bk1 = 0, bk2 = 0, bk3 = 0;

    for (int kt = kbase; kt < kbase + 256; kt += KTILE) {
        float acc[KTILE][PPT];
#pragma unroll
        for (int j = 0; j < KTILE; ++j)
#pragma unroll
            for (int pp = 0; pp < PPT; ++pp) acc[j][pp] = 0.f;

        // d-loop: partial unroll only (live set small); x float4 re-read
        // from L1 each K-tile (r2-proven absorbable); cb scalar s_loads.
#pragma unroll 2
        for (int d0 = 0; d0 < VQ_D; d0 += 4) {
#pragma unroll
            for (int dd = 0; dd < 4; ++dd) {
                const float4 xv =
                    *reinterpret_cast<const float4*>(xb + (d0 + dd) * VQ_HW);
                const float* cr = &cb[(d0 + dd) * VQ_K + kt];
#pragma unroll
                for (int j = 0; j < KTILE; ++j) {  // ascending-d FMA chains
                    const float c = cr[j];
                    acc[j][0] = fmaf(xv.x, c, acc[j][0]);
                    acc[j][1] = fmaf(xv.y, c, acc[j][1]);
                    acc[j][2] = fmaf(xv.z, c, acc[j][2]);
                    acc[j][3] = fmaf(xv.w, c, acc[j][3]);
                }
            }
        }
#pragma unroll
        for (int j = 0; j < KTILE; ++j) {
            const float se = sqe[kt + j];                 // scalar load
            const float dA = (sqx.x - 2.0f * acc[j][0]) + se;  // exact chain
            if (dA < best0) { best0 = dA; bk0 = kt + j; }
            const float dB = (sqx.y - 2.0f * acc[j][1]) + se;
            if (dB < best1) { best1 = dB; bk1 = kt + j; }
            const float dC = (sqx.z - 2.0f * acc[j][2]) + se;
            if (dC < best2) { best2 = dC; bk2 = kt + j; }
            const float dD = (sqx.w - 2.0f * acc[j][3]) + se;
            if (dD < best3) { best3 = dD; bk3 = kt + j; }
        }
    }

    // Publish per-half results; every wave recomputes the final min for its
    // own 4 positions (strict '<', half-0 preferred on tie = np.argmin).
    sbest[h][pblk + 0] = best0;  sbk[h][pblk + 0] = bk0;
    sbest[h][pblk + 1] = best1;  sbk[h][pblk + 1] = bk1;
    sbest[h][pblk + 2] = best2;  sbk[h][pblk + 2] = bk2;
    sbest[h][pblk + 3] = best3;  sbk[h][pblk + 3] = bk3;
    __syncthreads();

    int kf[PPT];
#pragma unroll
    for (int pp = 0; pp < PPT; ++pp) {
        const float b0 = sbest[0][pblk + pp];
        const float b1 = sbest[1][pblk + pp];
        kf[pp] = (b1 < b0) ? sbk[1][pblk + pp] : sbk[0][pblk + pp];
    }

    // Each k-half wave stores 32 of the 64 d-planes for its pos-group;
    // float4 over 4 consecutive positions -> 16B/lane coalesced stores.
    const int dbase = h << 5;
#pragma unroll 4
    for (int dd = 0; dd < 32; ++dd) {
        const int d = dbase + dd;
        float4 o;
        o.x = cb[d * VQ_K + kf[0]];
        o.y = cb[d * VQ_K + kf[1]];
        o.z = cb[d * VQ_K + kf[2]];
        o.w = cb[d * VQ_K + kf[3]];
        *reinterpret_cast<float4*>(ob + (size_t)d * VQ_HW) = o;
    }
}

extern "C" void kernel_launch(void* const* d_in, const int* in_sizes, int n_in,
                              void* d_out, int out_size, void* d_ws, size_t ws_size,
                              hipStream_t stream) {
    const float* enc = (const float*)d_in[0];  // [32,64,64,64]
    const float* cb  = (const float*)d_in[1];  // [64,512]
    float* out = (float*)d_out;
    float* sqe = (float*)d_ws;  // 512 floats

    vq_sqe_kernel<<<1, VQ_K, 0, stream>>>(cb, sqe);
    vq_main_kernel<<<VQ_N / POSB, 256, 0, stream>>>(enc, cb, sqe, out);
}

// Round 12
// 130.006 us; speedup vs baseline: 44.6047x; 2.0396x over previous
//
#include <hip/hip_runtime.h>

// VanillaVectorQuantizer: N=131072 positions (B=32,H=64,W=64), D=64, K=512.
// enc layout [B, D, H, W]: element (b,d,p) at b*D*HW + d*HW + p, p=h*64+w.
//
// Numerics: EXACT emulation of the numpy fp32 reference chain (verified
// bitwise rounds 2-11, absmax == 0):
//   - M_k: ascending-d fp32 FMA chain (== BLAS sgemm microkernel)
//   - sq_x: numpy pairwise_sum(n=64): 8 stride-8 accumulators of pre-rounded
//     squares (mul then add, NO fma), combine ((r0+r1)+(r2+r3))+((r4+r5)+(r6+r7))
//   - sq_e: sequential d-sum of pre-rounded squares (NO fma)
//   - dist: fl(fl(sq_x - fl(2*M)) + sq_e), contraction off
//   - strict '<' ascending k == np.argmin first-index tie-break
// DO NOT alter these chains.
//
// Model (calibrated r2..r11):
//   dur = max(VALU wall 131k cyc = 54.6us,
//             SMEM wall: 268MB/PPT @ 2.2 B/cyc/CU,
//             latency exposure when waves/SIMD low).
//   Scalar traffic = 268MB/PPT, INDEPENDENT of KSPLIT; occupancy =
//   N*KSPLIT/(64*PPT). r2/r8: PPT=1 -> traffic wall (200us, TLP-invariant).
//   r11: PPT=4,KSPLIT=2 -> 67MB but 1 wave/SIMD -> latency wall (265us,
//   VALU 27%). r9/r10: spills (fixed in r11: VGPR=48, clean traffic).
// This round: r11 inner body VERBATIM (proven non-spilling), KSPLIT 2->8:
// 8 waves/block over the same 256 positions, wave w scans k[64w,64w+64);
// 512 blocks = 2/CU = 4 waves/SIMD. Traffic stays 67MB (< VALU wall);
// x re-reads shared 8-way in L1/L2. LDS combine ascending wave = np.argmin.

#pragma clang fp contract(off)

#define VQ_D 64
#define VQ_K 512
#define VQ_HW 4096
#define VQ_N 131072
#define KTILE 8
#define PPT 4
#define NW 8      // waves per block = k-splits
#define POSB 256  // positions per block = 64 lanes * PPT

__global__ void vq_sqe_kernel(const float* __restrict__ cb,
                              float* __restrict__ sqe) {
    const int k = threadIdx.x;  // 512 threads, one block
    float s = cb[k] * cb[k];    // d = 0 (square rounded, then added: no fma)
    for (int d = 1; d < VQ_D; ++d) {
        const float v = cb[d * VQ_K + k];
        const float sq = v * v;  // contract(off): rounds the square
        s = s + sq;              // then rounds the add (numpy axis-0 reduce)
    }
    sqe[k] = s;
}

__global__ __launch_bounds__(512) void vq_main_kernel(
    const float* __restrict__ enc, const float* __restrict__ cb,
    const float* __restrict__ sqe, float* __restrict__ out) {
    __shared__ float sbest[NW][POSB];  // 8 KB
    __shared__ int sbk[NW][POSB];      // 8 KB

    const int tid = threadIdx.x;
    const int wid = tid >> 6;     // 0..7 == k-split
    const int lane = tid & 63;
    const int pos0 = blockIdx.x * POSB;  // 256 | 4096: block within one b
    const int b = pos0 >> 12;
    const int r0 = pos0 & (VQ_HW - 1);
    const int pblk = 4 * lane;    // first of this thread's 4 consecutive pos
    const float* xb = enc + (size_t)b * (VQ_D * VQ_HW) + r0 + pblk;
    float* ob = out + (size_t)b * (VQ_D * VQ_HW) + r0 + pblk;

    // k-range for this wave; readfirstlane -> SGPR, provably uniform ->
    // cb/sqe stay on the scalar-load path (the only viable transport).
    const int kbase = __builtin_amdgcn_readfirstlane(wid << 6);

    // sq_x for 4 consecutive positions (float4 = component-wise; chains
    // identical to the numpy pairwise_sum emulation; r10/r11-verified).
    float4 pr[8];
#pragma unroll
    for (int j = 0; j < 8; ++j) {
        const float4 v = *reinterpret_cast<const float4*>(xb + j * VQ_HW);
        pr[j] = v * v;  // rounded squares
    }
#pragma unroll
    for (int i8 = 8; i8 < VQ_D; i8 += 8) {
#pragma unroll
        for (int j = 0; j < 8; ++j) {
            const float4 v =
                *reinterpret_cast<const float4*>(xb + (i8 + j) * VQ_HW);
            const float4 sq = v * v;  // rounded squares
            pr[j] += sq;              // rounded adds
        }
    }
    const float4 sqx = ((pr[0] + pr[1]) + (pr[2] + pr[3])) +
                       ((pr[4] + pr[5]) + (pr[6] + pr[7]));

    float best0 = 3.402823466e38f, best1 = best0, best2 = best0, best3 = best0;
    int bk0 = 0, bk1 = 0, bk2 = 0, bk3 = 0;

    for (int kt = kbase; kt < kbase + 64; kt += KTILE) {
        float acc[KTILE][PPT];
#pragma unroll
        for (int j = 0; j < KTILE; ++j)
#pragma unroll
            for (int pp = 0; pp < PPT; ++pp) acc[j][pp] = 0.f;

        // d-loop: partial unroll (live set small, r11: VGPR=48, no spill);
        // x float4 re-read from L1/L2 each K-tile; cb scalar s_loads.
#pragma unroll 2
        for (int d0 = 0; d0 < VQ_D; d0 += 4) {
#pragma unroll
            for (int dd = 0; dd < 4; ++dd) {
                const float4 xv =
                    *reinterpret_cast<const float4*>(xb + (d0 + dd) * VQ_HW);
                const float* cr = &cb[(d0 + dd) * VQ_K + kt];
#pragma unroll
                for (int j = 0; j < KTILE; ++j) {  // ascending-d FMA chains
                    const float c = cr[j];
                    acc[j][0] = fmaf(xv.x, c, acc[j][0]);
                    acc[j][1] = fmaf(xv.y, c, acc[j][1]);
                    acc[j][2] = fmaf(xv.z, c, acc[j][2]);
                    acc[j][3] = fmaf(xv.w, c, acc[j][3]);
                }
            }
        }
#pragma unroll
        for (int j = 0; j < KTILE; ++j) {
            const float se = sqe[kt + j];                 // scalar load
            const float dA = (sqx.x - 2.0f * acc[j][0]) + se;  // exact chain
            if (dA < best0) { best0 = dA; bk0 = kt + j; }
            const float dB = (sqx.y - 2.0f * acc[j][1]) + se;
            if (dB < best1) { best1 = dB; bk1 = kt + j; }
            const float dC = (sqx.z - 2.0f * acc[j][2]) + se;
            if (dC < best2) { best2 = dC; bk2 = kt + j; }
            const float dD = (sqx.w - 2.0f * acc[j][3]) + se;
            if (dD < best3) { best3 = dD; bk3 = kt + j; }
        }
    }

    // Publish per-wave results; every thread recombines for its own 4
    // positions (ascending wave = ascending k-range, strict '<' keeps the
    // lowest k on ties = np.argmin first-index semantics, r8-proven).
    sbest[wid][pblk + 0] = best0;  sbk[wid][pblk + 0] = bk0;
    sbest[wid][pblk + 1] = best1;  sbk[wid][pblk + 1] = bk1;
    sbest[wid][pblk + 2] = best2;  sbk[wid][pblk + 2] = bk2;
    sbest[wid][pblk + 3] = best3;  sbk[wid][pblk + 3] = bk3;
    __syncthreads();

    int kf[PPT];
#pragma unroll
    for (int pp = 0; pp < PPT; ++pp) {
        float bb = sbest[0][pblk + pp];
        int k0 = sbk[0][pblk + pp];
#pragma unroll
        for (int s = 1; s < NW; ++s) {
            const float o = sbest[s][pblk + pp];
            if (o < bb) {
                bb = o;
                k0 = sbk[s][pblk + pp];
            }
        }
        kf[pp] = k0;
    }

    // Wave w stores d-planes [8w, 8w+8) for its 4 positions: float4 over 4
    // consecutive positions -> 16B/lane coalesced stores; cb gathers L1-hot.
    const int dbase = wid << 3;
#pragma unroll
    for (int dd = 0; dd < 8; ++dd) {
        const int d = dbase + dd;
        float4 o;
        o.x = cb[d * VQ_K + kf[0]];
        o.y = cb[d * VQ_K + kf[1]];
        o.z = cb[d * VQ_K + kf[2]];
        o.w = cb[d * VQ_K + kf[3]];
        *reinterpret_cast<float4*>(ob + (size_t)d * VQ_HW) = o;
    }
}

extern "C" void kernel_launch(void* const* d_in, const int* in_sizes, int n_in,
                              void* d_out, int out_size, void* d_ws, size_t ws_size,
                              hipStream_t stream) {
    const float* enc = (const float*)d_in[0];  // [32,64,64,64]
    const float* cb  = (const float*)d_in[1];  // [64,512]
    float* out = (float*)d_out;
    float* sqe = (float*)d_ws;  // 512 floats

    vq_sqe_kernel<<<1, VQ_K, 0, stream>>>(cb, sqe);
    vq_main_kernel<<<VQ_N / POSB, 512, 0, stream>>>(enc, cb, sqe, out);
}